// Round 15
// baseline (261.029 us; speedup 1.0000x reference)
//
#include <hip/hip_runtime.h>
#include <stdint.h>

typedef int v4i __attribute__((ext_vector_type(4)));

#define GLOBAL_AS __attribute__((address_space(1)))
#define LDS_AS __attribute__((address_space(3)))

// Exact replication of reference rounding:
// q = clamp(rint(x / s + z), 0, 255); store (q - zi) as int8.
__device__ __forceinline__ int quant1(float x, float s, float z, int zi) {
    float q = rintf(x / s + z);          // IEEE division + round-half-even, matches np
    q = fminf(fmaxf(q, 0.0f), 255.0f);
    return (int)q - zi;
}

__device__ __forceinline__ unsigned qpack4(float4 v, float s, float z, int zi) {
    unsigned q0 = (unsigned)(quant1(v.x, s, z, zi) & 255);
    unsigned q1 = (unsigned)(quant1(v.y, s, z, zi) & 255);
    unsigned q2 = (unsigned)(quant1(v.z, s, z, zi) & 255);
    unsigned q3 = (unsigned)(quant1(v.w, s, z, zi) & 255);
    return q0 | (q1 << 8) | (q2 << 16) | (q3 << 24);
}

// ---------------- quantize x1 (elementwise, keeps layout [*, K]) ----------------
__global__ __launch_bounds__(256) void quant_lin(const float* __restrict__ x,
                                                 int8_t* __restrict__ out,
                                                 const float* __restrict__ sp,
                                                 const float* __restrict__ zp,
                                                 long n16) {
    float s = sp[0], z = zp[0];
    int zi = (int)rintf(z);
    long i = (long)blockIdx.x * 256 + threadIdx.x;
    if (i >= n16) return;
    const float4* xv = (const float4*)x;
    uint4 w;
    w.x = qpack4(xv[i * 4 + 0], s, z, zi);
    w.y = qpack4(xv[i * 4 + 1], s, z, zi);
    w.z = qpack4(xv[i * 4 + 2], s, z, zi);
    w.w = qpack4(xv[i * 4 + 3], s, z, zi);
    ((uint4*)out)[i] = w;
}

// --- quantize x2 [K][N] -> int8, 16x16-BLOCK-major transposed layout ---
// B_blk: block (bn, bk) of B^T (rows n=bn*16.., k-bytes bk*16..) stored
// contiguously at ((bn*(K/16) + bk) * 256), element (n&15)*16 + (k&15).
// A GEMM wave's fragment read (16 rows x 16B, lane-consecutive) is then
// 1024 CONTIGUOUS bytes -> perfectly coalesced direct global load.
__global__ __launch_bounds__(256) void quant_bt(const float* __restrict__ x,
                                                int8_t* __restrict__ out,
                                                const float* __restrict__ sp,
                                                const float* __restrict__ zp) {
    constexpr int K = 4096, N = 4096;
    constexpr int KB = K / 16;  // 256 blocks per row of blocks
    float s = sp[0], z = zp[0];
    int zi = (int)rintf(z);
    size_t bin = (size_t)blockIdx.z * K * N;
    int tid = threadIdx.x;
    int bk = tid >> 4;   // 0..15: k-block of 4 rows
    int bn = tid & 15;   // 0..15: n-block of 4 cols
    int k0 = blockIdx.y * 64, n0 = blockIdx.x * 64;
    __shared__ unsigned lds[64][17];
    unsigned o0 = 0, o1 = 0, o2 = 0, o3 = 0;
#pragma unroll
    for (int r = 0; r < 4; ++r) {
        float4 v = *(const float4*)(x + bin + (size_t)(k0 + bk * 4 + r) * N + n0 + bn * 4);
        o0 |= (unsigned)(quant1(v.x, s, z, zi) & 255) << (r * 8);
        o1 |= (unsigned)(quant1(v.y, s, z, zi) & 255) << (r * 8);
        o2 |= (unsigned)(quant1(v.z, s, z, zi) & 255) << (r * 8);
        o3 |= (unsigned)(quant1(v.w, s, z, zi) & 255) << (r * 8);
    }
    lds[bn * 4 + 0][bk] = o0;
    lds[bn * 4 + 1][bk] = o1;
    lds[bn * 4 + 2][bk] = o2;
    lds[bn * 4 + 3][bk] = o3;
    __syncthreads();
    int nl = tid >> 2, ch = tid & 3;  // row n0+nl, k-chunk ch (16B)
    uint4 w;
    w.x = lds[nl][ch * 4 + 0];
    w.y = lds[nl][ch * 4 + 1];
    w.z = lds[nl][ch * 4 + 2];
    w.w = lds[nl][ch * 4 + 3];
    size_t blk_n = (size_t)(n0 >> 4) + (nl >> 4);
    size_t blk_k = (size_t)(k0 >> 4) + ch;
    *(uint4*)(out + bin + (blk_n * KB + blk_k) * 256 + (nl & 15) * 16) = w;
}

// ---- int8 GEMM: A via LDS ring-4/dist-3 (R9-verified), B direct global->reg ----
// C[b] = Aq[b](MxK) * B_blk[b]^T, mfma_i32_16x16x64_i8, BK=64.
// 512 threads = 8 waves (2Mx4N, 2/SIMD), wave 128x64, acc[8][4].
//
// Additive model (validated R5/R6/R9 within 5%): tile = MFMA_cyc + LDS_cyc.
// B bypasses LDS: blocked layout makes each fragment load 1024 contiguous
// B/wave (coalesced), L2-hot (panel reused by 8 blocks). LDS/tile falls
// 128KB -> 80KB (writes 16KB + A reads 64KB) => LDS term 960 < MFMA 1307.
//
// Tile t: ISSUE_A stage(t+3):2 -> LDB B(t+1)->regs:4 -> RD A slot(t+1):8 ->
//         32 MFMA on current frags -> vmcnt(6) -> s_barrier.
// Ledger (in-order retire): entering t outstanding = {A(t+2):2, B(t):4};
// issue {A(t+3):2, B(t+1):4} -> 12; compiler's B(t)-dependency wait before
// MM(t) = vmcnt(6), retiring A(t+2) and B(t); end-of-tile vmcnt(6) is the
// invariant guard (no-op steady-state). A(t+1) was retired during t-1 and
// published by t-1's barrier -> RD(t+1) safe. B-reg WAR: LDB writes parity
// (t+1)&1, MM reads parity t&1. A-slot WAR: slot(t+3)=slot(t-1). Tail:
// vmcnt 4 -> 0. Int accumulate: exact.
__global__ __launch_bounds__(512, 1) void gemm_i8(const int8_t* __restrict__ A,
                                                  const int8_t* __restrict__ Bblk,
                                                  float* __restrict__ C,
                                                  const float* __restrict__ sp1,
                                                  const float* __restrict__ sp2) {
    constexpr int M = 2048, N = 4096, K = 4096;
    constexpr int BM = 256, BN = 256, BK = 64;
    constexpr int NBN = N / BN;  // 16

    extern __shared__ char smem[];

    int b = blockIdx.z;
    const int8_t* Ab = A + (size_t)b * M * K;
    const int8_t* Bb = Bblk + (size_t)b * N * K;
    float* Cb = C + (size_t)b * M * N;

    // bijective XCD swizzle (grid.x = 128, % 8 == 0)
    int nwg = gridDim.x;
    int wg = blockIdx.x;
    wg = (wg & 7) * (nwg >> 3) + (wg >> 3);
    int by = wg / NBN, bx = wg % NBN;
    int m0 = by * BM, n0 = bx * BN;

    int tid = threadIdx.x;
    int lane = tid & 63, wid = tid >> 6;
    int wr = wid >> 2, wc = wid & 3;  // 2M x 4N
    int l15 = lane & 15, cb = lane >> 4;

    // A staging cursors (16 KB/tile, 2 gload_lds/thread, chunk-XOR swizzle)
    int row0 = tid >> 2, cc0 = tid & 3;
    int sw0 = cc0 ^ ((row0 >> 1) & 3);
    const size_t PSTEP = (size_t)128 * K;
    const int8_t* pA = Ab + (size_t)(m0 + row0) * K + sw0 * 16;  // += 64/tile
    const unsigned dbase = (unsigned)tid * 16;

    // A fragment ds_read base (swizzle invariant under row += 16)
    int ra = wr * 128 + l15;
    int aoff0 = ra * 64 + ((cb ^ ((ra >> 1) & 3)) * 16);

    // B direct-load cursor (blocked layout): fragment n of tile kt at
    // block_n(n) = bx*16 + wc*4 + n  ->  base + n*65536 + kt*1024 + lane*16
    const int8_t* pBv = Bb + ((size_t)(bx * 16 + wc * 4) << 16) + lane * 16;  // += 1024/tile

    v4i zero = {0, 0, 0, 0};
    v4i acc[8][4];
#pragma unroll
    for (int m = 0; m < 8; ++m)
#pragma unroll
        for (int n = 0; n < 4; ++n) acc[m][n] = zero;

    v4i fA0[8], fB0[4], fA1[8], fB1[4];

#define ISSUE_A(S)                                                                      \
    {                                                                                   \
        char* d = smem + (S)*16384 + dbase;                                             \
        __builtin_amdgcn_global_load_lds((const GLOBAL_AS void*)pA,                     \
                                         (LDS_AS void*)d, 16, 0, 0);                    \
        __builtin_amdgcn_global_load_lds((const GLOBAL_AS void*)(pA + PSTEP),           \
                                         (LDS_AS void*)(d + 8192), 16, 0, 0);           \
        pA += BK;                                                                       \
    }

#define LDB(fb)                                                                         \
    {                                                                                   \
        _Pragma("unroll") for (int n = 0; n < 4; ++n)                                   \
            fb[n] = *(const v4i*)(pBv + ((size_t)n << 16));                             \
        pBv += 1024;                                                                    \
    }

#define RDA(S, fa)                                                                      \
    {                                                                                   \
        const char* rbp = smem + (S)*16384;                                             \
        _Pragma("unroll") for (int m = 0; m < 8; ++m)                                   \
            fa[m] = *(const v4i*)(rbp + aoff0 + m * 1024);                              \
    }

#define MM(fa, fb)                                                                      \
    {                                                                                   \
        __builtin_amdgcn_s_setprio(1);                                                  \
        _Pragma("unroll") for (int m = 0; m < 8; ++m)                                   \
            _Pragma("unroll") for (int n = 0; n < 4; ++n)                               \
                acc[m][n] = __builtin_amdgcn_mfma_i32_16x16x64_i8(fa[m], fb[n],         \
                                                                  acc[m][n], 0, 0, 0);  \
        __builtin_amdgcn_s_setprio(0);                                                  \
    }

// encourage emission order [6 VMEM (2 A-stage + 4 B-loads)][8 ds_read][32 MFMA]
#define SGB3()                                                                          \
    __builtin_amdgcn_sched_group_barrier(0x30, 6, 0);                                   \
    __builtin_amdgcn_sched_group_barrier(0x100, 8, 0);                                  \
    __builtin_amdgcn_sched_group_barrier(0x8, 32, 0);

#define WAITBAR(NW)                                                                     \
    asm volatile("s_waitcnt vmcnt(" #NW ")" ::: "memory");                              \
    __builtin_amdgcn_s_barrier();                                                       \
    asm volatile("" ::: "memory");

#define STEP(SI, SR, CA, CBF, NA, NBF)                                                  \
    {                                                                                   \
        ISSUE_A(SI);                                                                    \
        LDB(NBF);                                                                       \
        RDA(SR, NA);                                                                    \
        MM(CA, CBF);                                                                    \
        SGB3();                                                                         \
        WAITBAR(6)                                                                      \
    }

    // prologue: A slots 0,1,2 (6 loads) + B(0) (4 loads).
    // vmcnt(6) retires A(0), A(1) (outstanding after: A(2):2 + B(0):4 = 6);
    // barrier publishes; read A(0) frags.
    ISSUE_A(0);
    ISSUE_A(1);
    ISSUE_A(2);
    LDB(fB0);
    WAITBAR(6)
    RDA(0, fA0);

    // t = 0..59 : 15 x unroll-4; tile t: stage A slot (t+3)&3, read A (t+1)&3,
    // load B(t+1) into parity regs, compute tile t.
    for (int it = 0; it < 15; ++it) {
        STEP(3, 1, fA0, fB0, fA1, fB1)   // t%4==0
        STEP(0, 2, fA1, fB1, fA0, fB0)   // t%4==1
        STEP(1, 3, fA0, fB0, fA1, fB1)   // t%4==2
        STEP(2, 0, fA1, fB1, fA0, fB0)   // t%4==3
    }
    // t = 60: last A stage (tile 63 -> slot 3)
    STEP(3, 1, fA0, fB0, fA1, fB1)
    // t = 61: B(62); retire A(63) (outstanding after wait: B(62):4)
    {
        LDB(fB0);
        RDA(2, fA0);
        MM(fA1, fB1);
        WAITBAR(4)
    }
    // t = 62: B(63); full drain so MM(63)'s operands are complete
    {
        LDB(fB1);
        RDA(3, fA1);
        MM(fA0, fB0);
        WAITBAR(0)
    }
    // t = 63
    MM(fA1, fB1);

    float sc = sp1[0] * sp2[0];
    int r0 = cb * 4;
#pragma unroll
    for (int m = 0; m < 8; ++m) {
#pragma unroll
        for (int n = 0; n < 4; ++n) {
            float* p = Cb + (size_t)(m0 + wr * 128 + m * 16 + r0) * N +
                       (n0 + wc * 64 + n * 16 + l15);
#pragma unroll
            for (int r = 0; r < 4; ++r) p[(size_t)r * N] = sc * (float)acc[m][n][r];
        }
    }
#undef ISSUE_A
#undef LDB
#undef RDA
#undef MM
#undef SGB3
#undef WAITBAR
#undef STEP
}

extern "C" void kernel_launch(void* const* d_in, const int* in_sizes, int n_in,
                              void* d_out, int out_size, void* d_ws, size_t ws_size,
                              hipStream_t stream) {
    const float* x1 = (const float*)d_in[0];
    const float* x2 = (const float*)d_in[1];
    const float* s1 = (const float*)d_in[2];
    const float* z1 = (const float*)d_in[3];
    const float* s2 = (const float*)d_in[4];
    const float* z2 = (const float*)d_in[5];
    float* out = (float*)d_out;

    const int B = 4, M = 2048, K = 4096, N = 4096;
    const size_t ASZ = (size_t)B * M * K;
    const size_t BSZ = (size_t)B * K * N;
    dim3 blk(256);

    static int lds_attr_set = 0;
    if (!lds_attr_set) {
        (void)hipFuncSetAttribute((const void*)gemm_i8,
                                  hipFuncAttributeMaxDynamicSharedMemorySize, 65536);
        lds_attr_set = 1;
    }

    if (ws_size >= ASZ + BSZ) {
        int8_t* Aq = (int8_t*)d_ws;
        int8_t* Bq = Aq + ASZ;
        long n16 = (long)(ASZ / 16);
        quant_lin<<<dim3((unsigned)(n16 / 256)), blk, 0, stream>>>(x1, Aq, s1, z1, n16);
        quant_bt<<<dim3(N / 64, K / 64, B), blk, 0, stream>>>(x2, Bq, s2, z2);
        gemm_i8<<<dim3((M / 256) * (N / 256), 1, B), dim3(512), 65536, stream>>>(
            Aq, Bq, out, s1, s2);
    } else {
        const size_t AB = (size_t)M * K, BB = (size_t)K * N;
        int8_t* Aq = (int8_t*)d_ws;
        int8_t* Bq = Aq + AB;
        for (int b = 0; b < B; ++b) {
            long n16 = (long)(AB / 16);
            quant_lin<<<dim3((unsigned)(n16 / 256)), blk, 0, stream>>>(x1 + (size_t)b * AB, Aq, s1, z1, n16);
            quant_bt<<<dim3(N / 64, K / 64, 1), blk, 0, stream>>>(x2 + (size_t)b * BB, Bq, s2, z2);
            gemm_i8<<<dim3((M / 256) * (N / 256), 1, 1), dim3(512), 65536, stream>>>(
                Aq, Bq, out + (size_t)b * M * N, s1, s2);
        }
    }
}

// Round 16
// 249.832 us; speedup vs baseline: 1.0448x; 1.0448x over previous
//
#include <hip/hip_runtime.h>
#include <stdint.h>

typedef int v4i __attribute__((ext_vector_type(4)));

#define GLOBAL_AS __attribute__((address_space(1)))
#define LDS_AS __attribute__((address_space(3)))

// Exact replication of reference rounding:
// q = clamp(rint(x / s + z), 0, 255); store (q - zi) as int8.
__device__ __forceinline__ int quant1(float x, float s, float z, int zi) {
    float q = rintf(x / s + z);          // IEEE division + round-half-even, matches np
    q = fminf(fmaxf(q, 0.0f), 255.0f);
    return (int)q - zi;
}

__device__ __forceinline__ unsigned qpack4(float4 v, float s, float z, int zi) {
    unsigned q0 = (unsigned)(quant1(v.x, s, z, zi) & 255);
    unsigned q1 = (unsigned)(quant1(v.y, s, z, zi) & 255);
    unsigned q2 = (unsigned)(quant1(v.z, s, z, zi) & 255);
    unsigned q3 = (unsigned)(quant1(v.w, s, z, zi) & 255);
    return q0 | (q1 << 8) | (q2 << 16) | (q3 << 24);
}

// ---------------- quantize x1 (elementwise, keeps layout [*, K]) ----------------
__global__ __launch_bounds__(256) void quant_lin(const float* __restrict__ x,
                                                 int8_t* __restrict__ out,
                                                 const float* __restrict__ sp,
                                                 const float* __restrict__ zp,
                                                 long n16) {
    float s = sp[0], z = zp[0];
    int zi = (int)rintf(z);
    long i = (long)blockIdx.x * 256 + threadIdx.x;
    if (i >= n16) return;
    const float4* xv = (const float4*)x;
    uint4 w;
    w.x = qpack4(xv[i * 4 + 0], s, z, zi);
    w.y = qpack4(xv[i * 4 + 1], s, z, zi);
    w.z = qpack4(xv[i * 4 + 2], s, z, zi);
    w.w = qpack4(xv[i * 4 + 3], s, z, zi);
    ((uint4*)out)[i] = w;
}

// ------------- quantize x2 [K][N] -> int8 transposed [N][K] -------------
__global__ __launch_bounds__(256) void quant_bt(const float* __restrict__ x,
                                                int8_t* __restrict__ out,
                                                const float* __restrict__ sp,
                                                const float* __restrict__ zp) {
    constexpr int K = 4096, N = 4096;
    float s = sp[0], z = zp[0];
    int zi = (int)rintf(z);
    size_t bin = (size_t)blockIdx.z * K * N;
    int tid = threadIdx.x;
    int bk = tid >> 4;   // 0..15: k-block of 4 rows
    int bn = tid & 15;   // 0..15: n-block of 4 cols
    int k0 = blockIdx.y * 64, n0 = blockIdx.x * 64;
    __shared__ unsigned lds[64][17];
    unsigned o0 = 0, o1 = 0, o2 = 0, o3 = 0;
#pragma unroll
    for (int r = 0; r < 4; ++r) {
        float4 v = *(const float4*)(x + bin + (size_t)(k0 + bk * 4 + r) * N + n0 + bn * 4);
        o0 |= (unsigned)(quant1(v.x, s, z, zi) & 255) << (r * 8);
        o1 |= (unsigned)(quant1(v.y, s, z, zi) & 255) << (r * 8);
        o2 |= (unsigned)(quant1(v.z, s, z, zi) & 255) << (r * 8);
        o3 |= (unsigned)(quant1(v.w, s, z, zi) & 255) << (r * 8);
    }
    lds[bn * 4 + 0][bk] = o0;
    lds[bn * 4 + 1][bk] = o1;
    lds[bn * 4 + 2][bk] = o2;
    lds[bn * 4 + 3][bk] = o3;
    __syncthreads();
    int nl = tid >> 2, ch = tid & 3;
    uint4 w;
    w.x = lds[nl][ch * 4 + 0];
    w.y = lds[nl][ch * 4 + 1];
    w.z = lds[nl][ch * 4 + 2];
    w.w = lds[nl][ch * 4 + 3];
    *(uint4*)(out + bin + (size_t)(n0 + nl) * K + k0 + ch * 16) = w;
}

// ---- int8 GEMM, 256x256 tile, BK=64, ring-4 LDS, issue-dist-3, reg-dbuf ----
// C[b] = Aq[b](MxK) * BqT[b](NxK)^T, mfma_i32_16x16x64_i8.
// 512 threads = 8 waves (2Mx4N, 2/SIMD), wave 128x64, acc[8][4] (128 regs).
// LDS 128 KiB = ring of 4 slots x [A 16K | B 16K] -> 1 block/CU.
//
// Tile t: ISSUE stage(t+3) -> RD slot(t+1) into NEXT frag regs ->
//         32 MFMA on CURRENT frag regs -> vmcnt(4) -> s_barrier.
//
// RAW ledger (4 loads/ISSUE, in-order retire): at end of tile t-1 the
// outstanding set is {stage(t+1):4, stage(t+2):4}; its vmcnt(4) retires
// stage(t+1) and the s_barrier publishes it to ALL waves -- so RD(t+1)
// in tile t is safe.
// MFMA depends on nothing issued this tile (frags read last tile, lgkm
// drained by register dep before first MFMA) -> the 12 ds_reads drain
// under the 1306-cyc MFMA cluster instead of serializing before it.
// WAR: slot(t+3)=slot(t-1), last consumed before tile t-1's barrier.
// In-flight stage time = 2 tiles >> 900-cyc HBM. Int accumulate: exact.
//
// FINAL SESSION VERDICT (R0-R15): verified optimum, 151 us GEMM / 250 us
// total (1815 TOPS, 40% MfmaUtil). All levers isolated and refuted:
// coarser/finer barriers (R3/R12), 32x32 MFMA (R4), block de-phasing (R6),
// 1 wave/SIMD (R7), deeper pipeline (R10/R13), LDS-bypass B both
// row-major (R11) and blocked-coalesced (R15). i8's LDS term (~1540
// cyc/tile) >= its MFMA term (~1307); the pipes serialize from HIP source
// across every schedule tried -- tile_time = sum, not max.
__global__ __launch_bounds__(512, 1) void gemm_i8(const int8_t* __restrict__ A,
                                                  const int8_t* __restrict__ Bt,
                                                  float* __restrict__ C,
                                                  const float* __restrict__ sp1,
                                                  const float* __restrict__ sp2) {
    constexpr int M = 2048, N = 4096, K = 4096;
    constexpr int BM = 256, BN = 256, BK = 64;
    constexpr int NBN = N / BN;  // 16

    extern __shared__ char smem[];

    int b = blockIdx.z;
    const int8_t* Ab = A + (size_t)b * M * K;
    const int8_t* Bb = Bt + (size_t)b * N * K;
    float* Cb = C + (size_t)b * M * N;

    // XCD-aware swizzle; grid.x = 128, divisible by 8 -> bijective
    int nwg = gridDim.x;
    int wg = blockIdx.x;
    wg = (wg & 7) * (nwg >> 3) + (wg >> 3);
    int by = wg / NBN, bx = wg % NBN;
    int m0 = by * BM, n0 = bx * BN;

    int tid = threadIdx.x;
    int lane = tid & 63, wid = tid >> 6;
    int wr = wid >> 2, wc = wid & 3;  // 2M x 4N
    int l15 = lane & 15, cb = lane >> 4;

    // staging cursors: p in {0,1} -> row = p*128 + (tid>>2),
    // chunk = (tid&3) ^ ((row>>1)&3) (row+128 leaves swizzle invariant)
    int row0 = tid >> 2, cc0 = tid & 3;
    int sw0 = cc0 ^ ((row0 >> 1) & 3);
    const size_t PSTEP = (size_t)128 * K;
    const int8_t* pA = Ab + (size_t)(m0 + row0) * K + sw0 * 16;  // += 64/tile
    const int8_t* pB = Bb + (size_t)(n0 + row0) * K + sw0 * 16;
    const unsigned dbase = (unsigned)tid * 16;

    // fragment ds_read base offsets; m/n strides (1024 B) fold into the
    // ds_read immediate (swizzle term invariant under row += 16)
    int ra = wr * 128 + l15;
    int aoff0 = ra * 64 + ((cb ^ ((ra >> 1) & 3)) * 16);
    int rb_ = wc * 64 + l15;
    int boff0 = 16384 + rb_ * 64 + ((cb ^ ((rb_ >> 1) & 3)) * 16);

    v4i zero = {0, 0, 0, 0};
    v4i acc[8][4];
#pragma unroll
    for (int m = 0; m < 8; ++m)
#pragma unroll
        for (int n = 0; n < 4; ++n) acc[m][n] = zero;

    v4i fA0[8], fB0[4], fA1[8], fB1[4];

#define ISSUE(S)                                                                        \
    {                                                                                   \
        char* d = smem + (S)*32768 + dbase;                                             \
        __builtin_amdgcn_global_load_lds((const GLOBAL_AS void*)pA,                     \
                                         (LDS_AS void*)d, 16, 0, 0);                    \
        __builtin_amdgcn_global_load_lds((const GLOBAL_AS void*)(pA + PSTEP),           \
                                         (LDS_AS void*)(d + 8192), 16, 0, 0);           \
        __builtin_amdgcn_global_load_lds((const GLOBAL_AS void*)pB,                     \
                                         (LDS_AS void*)(d + 16384), 16, 0, 0);          \
        __builtin_amdgcn_global_load_lds((const GLOBAL_AS void*)(pB + PSTEP),           \
                                         (LDS_AS void*)(d + 24576), 16, 0, 0);          \
        pA += BK;                                                                       \
        pB += BK;                                                                       \
    }

#define RD(S, fa, fb)                                                                   \
    {                                                                                   \
        const char* rbp = smem + (S)*32768;                                             \
        _Pragma("unroll") for (int n = 0; n < 4; ++n)                                   \
            fb[n] = *(const v4i*)(rbp + boff0 + n * 1024);                              \
        _Pragma("unroll") for (int m = 0; m < 8; ++m)                                   \
            fa[m] = *(const v4i*)(rbp + aoff0 + m * 1024);                              \
    }

#define MM(fa, fb)                                                                      \
    {                                                                                   \
        __builtin_amdgcn_s_setprio(1);                                                  \
        _Pragma("unroll") for (int m = 0; m < 8; ++m)                                   \
            _Pragma("unroll") for (int n = 0; n < 4; ++n)                               \
                acc[m][n] = __builtin_amdgcn_mfma_i32_16x16x64_i8(fa[m], fb[n],         \
                                                                  acc[m][n], 0, 0, 0);  \
        __builtin_amdgcn_s_setprio(0);                                                  \
    }

// encourage emission order [4 VMEM stage][12 ds_read][32 MFMA]
#define SGB3()                                                                          \
    __builtin_amdgcn_sched_group_barrier(0x30, 4, 0);                                   \
    __builtin_amdgcn_sched_group_barrier(0x100, 12, 0);                                 \
    __builtin_amdgcn_sched_group_barrier(0x8, 32, 0);

#define STEP(SI, SR, CA, CB, NA, NB)                                                    \
    {                                                                                   \
        ISSUE(SI);                                                                      \
        RD(SR, NA, NB);                                                                 \
        MM(CA, CB);                                                                     \
        SGB3();                                                                         \
        asm volatile("s_waitcnt vmcnt(4)" ::: "memory");                                \
        __builtin_amdgcn_s_barrier();                                                   \
        asm volatile("" ::: "memory");                                                  \
    }

    // prologue: stage tiles 0,1,2; retire 0 AND 1 (leave 2 in flight);
    // barrier publishes; read tile 0 fragments.
    ISSUE(0);
    ISSUE(1);
    ISSUE(2);
    asm volatile("s_waitcnt vmcnt(4)" ::: "memory");
    __builtin_amdgcn_s_barrier();
    asm volatile("" ::: "memory");
    RD(0, fA0, fB0);

    // t = 0..59 : 15 x unroll-4; tile t: issue slot (t+3)&3, read slot (t+1)&3
    for (int it = 0; it < 15; ++it) {
        STEP(3, 1, fA0, fB0, fA1, fB1)   // t%4==0
        STEP(0, 2, fA1, fB1, fA0, fB0)   // t%4==1
        STEP(1, 3, fA0, fB0, fA1, fB1)   // t%4==2
        STEP(2, 0, fA1, fB1, fA0, fB0)   // t%4==3
    }
    // t = 60: issue stage(63) -> slot 3; read tile 61 (slot 1); compute 60
    STEP(3, 1, fA0, fB0, fA1, fB1)
    // t = 61: no issue; read tile 62 (slot 2, retired at t=60's vmcnt(4));
    // compute 61; drain stage(63) fully + barrier before anyone reads slot 3
    {
        RD(2, fA0, fB0);
        MM(fA1, fB1);
        asm volatile("s_waitcnt vmcnt(0)" ::: "memory");
        __builtin_amdgcn_s_barrier();
        asm volatile("" ::: "memory");
    }
    // t = 62: read tile 63 (slot 3, now landed); compute 62
    RD(3, fA1, fB1);
    MM(fA0, fB0);
    // t = 63
    MM(fA1, fB1);

    float sc = sp1[0] * sp2[0];
    int r0 = cb * 4;
#pragma unroll
    for (int m = 0; m < 8; ++m) {
#pragma unroll
        for (int n = 0; n < 4; ++n) {
            float* p = Cb + (size_t)(m0 + wr * 128 + m * 16 + r0) * N +
                       (n0 + wc * 64 + n * 16 + l15);
#pragma unroll
            for (int r = 0; r < 4; ++r) p[(size_t)r * N] = sc * (float)acc[m][n][r];
        }
    }
#undef ISSUE
#undef RD
#undef MM
#undef SGB3
#undef STEP
}

extern "C" void kernel_launch(void* const* d_in, const int* in_sizes, int n_in,
                              void* d_out, int out_size, void* d_ws, size_t ws_size,
                              hipStream_t stream) {
    const float* x1 = (const float*)d_in[0];
    const float* x2 = (const float*)d_in[1];
    const float* s1 = (const float*)d_in[2];
    const float* z1 = (const float*)d_in[3];
    const float* s2 = (const float*)d_in[4];
    const float* z2 = (const float*)d_in[5];
    float* out = (float*)d_out;

    const int B = 4, M = 2048, K = 4096, N = 4096;
    const size_t ASZ = (size_t)B * M * K;
    const size_t BSZ = (size_t)B * K * N;
    dim3 blk(256);

    static int lds_attr_set = 0;
    if (!lds_attr_set) {
        (void)hipFuncSetAttribute((const void*)gemm_i8,
                                  hipFuncAttributeMaxDynamicSharedMemorySize, 131072);
        lds_attr_set = 1;
    }

    if (ws_size >= ASZ + BSZ) {
        int8_t* Aq = (int8_t*)d_ws;
        int8_t* Bq = Aq + ASZ;
        long n16 = (long)(ASZ / 16);
        quant_lin<<<dim3((unsigned)(n16 / 256)), blk, 0, stream>>>(x1, Aq, s1, z1, n16);
        quant_bt<<<dim3(N / 64, K / 64, B), blk, 0, stream>>>(x2, Bq, s2, z2);
        gemm_i8<<<dim3((M / 256) * (N / 256), 1, B), dim3(512), 131072, stream>>>(
            Aq, Bq, out, s1, s2);
    } else {
        const size_t AB = (size_t)M * K, BB = (size_t)K * N;
        int8_t* Aq = (int8_t*)d_ws;
        int8_t* Bq = Aq + AB;
        for (int b = 0; b < B; ++b) {
            long n16 = (long)(AB / 16);
            quant_lin<<<dim3((unsigned)(n16 / 256)), blk, 0, stream>>>(x1 + (size_t)b * AB, Aq, s1, z1, n16);
            quant_bt<<<dim3(N / 64, K / 64, 1), blk, 0, stream>>>(x2 + (size_t)b * BB, Bq, s2, z2);
            gemm_i8<<<dim3((M / 256) * (N / 256), 1, 1), dim3(512), 131072, stream>>>(
                Aq, Bq, out + (size_t)b * M * N, s1, s2);
        }
    }
}